// Round 8
// baseline (77.958 us; speedup 1.0000x reference)
//
#include <hip/hip_runtime.h>

constexpr int NB = 4;
constexpr int CC = 128;
constexpr int HH = 64;
constexpr int WW = 64;
constexpr int HWp = HH * WW;      // 4096
constexpr int NHEADS = 4;
constexpr int K2 = 25;

typedef unsigned int   uint32;
typedef unsigned short ushort16;
typedef __attribute__((ext_vector_type(8))) short bf16x8;
typedef __attribute__((ext_vector_type(4))) float f32x4;

__device__ __forceinline__ ushort16 f2bf(float x) {
    uint32 b = __float_as_uint(x);
    return (ushort16)((b + 0x7FFFu + ((b >> 16) & 1u)) >> 16);   // RNE
}
__device__ __forceinline__ uint32 pack2(float lo, float hi) {
    return ((uint32)f2bf(hi) << 16) | (uint32)f2bf(lo);
}
__device__ __forceinline__ float bf_lo(uint32 u) { return __uint_as_float(u << 16); }
__device__ __forceinline__ float bf_hi(uint32 u) { return __uint_as_float(u & 0xFFFF0000u); }

// ---------------------------------------------------------------------------
// Kernel 0: convert Wq/Wk/Wv/Wfc fp32 -> bf16 (row-major preserved).
// ---------------------------------------------------------------------------
__global__ __launch_bounds__(256) void wconv_kernel(
    const float* __restrict__ Wq, const float* __restrict__ Wk,
    const float* __restrict__ Wv, const float* __restrict__ Wfc,
    ushort16* __restrict__ wbf)
{
    int i = blockIdx.x * 256 + threadIdx.x;   // 0..16383
    int m = i >> 12;
    int j = i & 4095;
    const float* s = (m == 0) ? Wq : ((m == 1) ? Wk : ((m == 2) ? Wv : Wfc));
    float4 f = reinterpret_cast<const float4*>(s)[j];
    uint32 w0 = pack2(f.x, f.y);
    uint32 w1 = pack2(f.z, f.w);
    uint32* d = reinterpret_cast<uint32*>(wbf + (size_t)m * 16384);
    d[j * 2]     = w0;
    d[j * 2 + 1] = w1;
}

// ---------------------------------------------------------------------------
// Kernel 1: MFMA projections. C[out=128][pix] = W[128x128] * X[c=128][pix].
// grid = 3 * NB * 64 = 768 blocks, 256 threads (2x2 wave grid).
// ---------------------------------------------------------------------------
__global__ __launch_bounds__(256) void proj_mfma(
    const float* __restrict__ q, const float* __restrict__ k, const float* __restrict__ v,
    const ushort16* __restrict__ wbf,
    ushort16* __restrict__ qp, ushort16* __restrict__ kp, ushort16* __restrict__ vp)
{
    __shared__ __align__(16) ushort16 lx[64 * 132];

    int blk = blockIdx.x;
    int p   = blk >> 8;
    int rem = blk & 255;
    int n   = rem >> 6;
    int pt  = rem & 63;
    int pix0 = pt * 64;

    const float*    X  = (p == 0) ? q  : ((p == 1) ? k  : v);
    ushort16*       O  = (p == 0) ? qp : ((p == 1) ? kp : vp);
    const ushort16* Wb = wbf + (size_t)p * 16384;
    const float*    Xb = X + (size_t)n * CC * HWp + pix0;

    int lane = threadIdx.x & 63;
    int cg   = threadIdx.x >> 6;

#pragma unroll
    for (int i = 0; i < 16; ++i) {
        int c0 = i * 8 + cg * 2;
        float a = Xb[c0 * HWp + lane];
        float b = Xb[(c0 + 1) * HWp + lane];
        *reinterpret_cast<uint32*>(&lx[lane * 132 + c0]) = pack2(a, b);
    }
    __syncthreads();

    int wid = threadIdx.x >> 6;
    int wr  = wid >> 1, wc = wid & 1;
    int p16 = lane & 15, kg = lane >> 4;

    f32x4 acc[4][2] = {};

#pragma unroll
    for (int k0 = 0; k0 < 128; k0 += 32) {
        bf16x8 A[4], B[2];
#pragma unroll
        for (int ai = 0; ai < 4; ++ai) {
            int o = wr * 64 + ai * 16 + p16;
            A[ai] = *reinterpret_cast<const bf16x8*>(&Wb[o * 128 + k0 + kg * 8]);
        }
#pragma unroll
        for (int bj = 0; bj < 2; ++bj) {
            int px = wc * 32 + bj * 16 + p16;
            const ushort16* sp = &lx[px * 132 + k0 + kg * 8];
            struct { unsigned long long lo, hi; } t;
            t.lo = *reinterpret_cast<const unsigned long long*>(sp);
            t.hi = *reinterpret_cast<const unsigned long long*>(sp + 4);
            B[bj] = __builtin_bit_cast(bf16x8, t);
        }
#pragma unroll
        for (int ai = 0; ai < 4; ++ai)
#pragma unroll
            for (int bj = 0; bj < 2; ++bj)
                acc[ai][bj] = __builtin_amdgcn_mfma_f32_16x16x32_bf16(
                    A[ai], B[bj], acc[ai][bj], 0, 0, 0);
    }

    ushort16* Ob = O + (size_t)(n * HWp + pix0) * CC;
#pragma unroll
    for (int ai = 0; ai < 4; ++ai) {
        int ob = wr * 64 + ai * 16 + kg * 4;
#pragma unroll
        for (int bj = 0; bj < 2; ++bj) {
            int px = wc * 32 + bj * 16 + p16;
            uint32* dst = reinterpret_cast<uint32*>(&Ob[(size_t)px * CC + ob]);
            dst[0] = pack2(acc[ai][bj][0], acc[ai][bj][1]);
            dst[1] = pack2(acc[ai][bj][2], acc[ai][bj][3]);
        }
    }
}

// ---------------------------------------------------------------------------
// Kernel 2: fused flow sampling + multi-head attention.
// ONE pixel per 64-lane wave, 2 channels/lane: every gather is 64x4B =
// 256B contiguous (2 cache-line segments). 16384 waves -> deep per-SIMD
// wave turnover hides gather latency. oh written IN-PLACE over qp.
// ---------------------------------------------------------------------------

#define KVLOAD1(BUF, BASE, R) { \
    const ushort16* r_ = (BASE) + roff[R]; \
    _Pragma("unroll") \
    for (int rx = 0; rx < 6; ++rx) \
        BUF[rx] = *reinterpret_cast<const uint32*>(r_ + coff[rx]); }

#define KCONSUME1(BUF, R) { \
    float pd_[6]; \
    _Pragma("unroll") \
    for (int rx = 0; rx < 6; ++rx) \
        pd_[rx] = fmaf(q1, bf_hi(BUF[rx]), q0 * bf_lo(BUF[rx])); \
    float hbr_[5]; \
    _Pragma("unroll") \
    for (int kx = 0; kx < 5; ++kx) \
        hbr_[kx] = pd_[kx] * XA[kx] + pd_[kx + 1] * XB[kx + 1]; \
    if ((R) < 5) { \
        _Pragma("unroll") \
        for (int kx = 0; kx < 5; ++kx) l[(R) * 5 + kx] = hbr_[kx] * YT[R]; } \
    if ((R) >= 1) { \
        _Pragma("unroll") \
        for (int kx = 0; kx < 5; ++kx) \
            l[((R) - 1) * 5 + kx] = fmaf(hbr_[kx], YB[R], l[((R) - 1) * 5 + kx]); } }

#define VCONSUME1(BUF, R) { \
    float lhc_[6]; \
    if ((R) < 5) { \
        lhc_[0] = l[(R) * 5 + 0] * XA[0]; \
        _Pragma("unroll") \
        for (int rx = 1; rx < 5; ++rx) \
            lhc_[rx] = l[(R) * 5 + rx] * XA[rx] + l[(R) * 5 + rx - 1] * XB[rx]; \
        lhc_[5] = l[(R) * 5 + 4] * XB[5]; \
    } else { \
        _Pragma("unroll") \
        for (int rx = 0; rx < 6; ++rx) lhc_[rx] = 0.f; \
    } \
    _Pragma("unroll") \
    for (int rx = 0; rx < 6; ++rx) { \
        float w6_ = lhc_[rx] * YT[R] + lhp[rx] * YB[R]; \
        uint32 u_ = BUF[rx]; \
        acc0 = fmaf(bf_lo(u_), w6_, acc0); \
        acc1 = fmaf(bf_hi(u_), w6_, acc1); \
    } \
    _Pragma("unroll") \
    for (int rx = 0; rx < 6; ++rx) lhp[rx] = lhc_[rx]; }

__global__ __launch_bounds__(64, 4) void attn_kernel(
    ushort16* qoh,
    const ushort16* __restrict__ kp, const ushort16* __restrict__ vp,
    const float* __restrict__ flow,
    float* __restrict__ attn)
{
    int blk = blockIdx.x;                        // 0..16383
    int pix = ((blk & 7) << 11) + (blk >> 3);    // XCD-contiguous pixel bands
    int lane = threadIdx.x;                      // 0..63
    int c0  = lane * 2;
    int n   = pix >> 12;
    int yx  = pix & 4095;
    int y   = yx >> 6, x = yx & 63;

    float fx = flow[((size_t)n * 2 + 0) * HWp + yx];
    float fy = flow[((size_t)n * 2 + 1) * HWp + yx];
    float pxf = (float)x + fx, pyf = (float)y + fy;
    float X0 = floorf(pxf), Y0 = floorf(pyf);
    float wx = pxf - X0,    wy = pyf - Y0;
    int ix0 = (int)X0 - 2,  iy0 = (int)Y0 - 2;

    int coff[6], roff[6];
    float XA[6], XB[6], YT[6], YB[6];
#pragma unroll
    for (int r = 0; r < 6; ++r) {
        int xi = ix0 + r;
        float mx = (xi >= 0 && xi < WW) ? 1.f : 0.f;
        int xc = xi < 0 ? 0 : (xi > WW - 1 ? WW - 1 : xi);
        coff[r] = xc * CC;
        XA[r] = (1.f - wx) * mx;
        XB[r] = wx * mx;
        int yi = iy0 + r;
        float my = (yi >= 0 && yi < HH) ? 1.f : 0.f;
        int yc = yi < 0 ? 0 : (yi > HH - 1 ? HH - 1 : yi);
        roff[r] = yc * (WW * CC);
        YT[r] = (1.f - wy) * my;
        YB[r] = wy * my;
    }

    const ushort16* kb  = kp + (size_t)n * HWp * CC + c0;
    const ushort16* vbp = vp + (size_t)n * HWp * CC + c0;
    ushort16* qb = qoh + (size_t)pix * CC + c0;

    uint32 qpk = *reinterpret_cast<const uint32*>(qb);
    float q0 = bf_lo(qpk), q1 = bf_hi(qpk);

    // ---- K pass: 2-buffer row pipeline (6 x 4B-contiguous loads/row) ----
    float l[25];
    {
        uint32 kA[6], kB[6];
        KVLOAD1(kA, kb, 0)
        KVLOAD1(kB, kb, 1)
        KCONSUME1(kA, 0)
        KVLOAD1(kA, kb, 2)
        KCONSUME1(kB, 1)
        KVLOAD1(kB, kb, 3)
        KCONSUME1(kA, 2)
        KVLOAD1(kA, kb, 4)
        KCONSUME1(kB, 3)
        KVLOAD1(kB, kb, 5)
        KCONSUME1(kA, 4)
        KCONSUME1(kB, 5)
    }

    // ---- V prologue: issued before softmax so latency hides under VALU ----
    uint32 vA[6], vB[6];
    KVLOAD1(vA, vbp, 0)
    KVLOAD1(vB, vbp, 1)

    // ---- reduce over 16 lanes (= 32 channels) of this head ----
#pragma unroll
    for (int kk = 0; kk < 25; ++kk) {
        float s = l[kk];
        s += __shfl_xor(s, 1);
        s += __shfl_xor(s, 2);
        s += __shfl_xor(s, 4);
        s += __shfl_xor(s, 8);
        l[kk] = s * 0.17677669529663687f;   // 1/sqrt(32)
    }

    // ---- softmax over 25 ----
    float m = l[0];
#pragma unroll
    for (int kk = 1; kk < 25; ++kk) m = fmaxf(m, l[kk]);
    float sum = 0.f;
#pragma unroll
    for (int kk = 0; kk < 25; ++kk) { l[kk] = __expf(l[kk] - m); sum += l[kk]; }
    float inv = 1.f / sum;
#pragma unroll
    for (int kk = 0; kk < 25; ++kk) l[kk] *= inv;

    // ---- V pass: 2-buffer row pipeline ----
    float acc0 = 0.f, acc1 = 0.f;
    float lhp[6] = {0.f, 0.f, 0.f, 0.f, 0.f, 0.f};
    VCONSUME1(vA, 0)
    KVLOAD1(vA, vbp, 2)
    VCONSUME1(vB, 1)
    KVLOAD1(vB, vbp, 3)
    VCONSUME1(vA, 2)
    KVLOAD1(vA, vbp, 4)
    VCONSUME1(vB, 3)
    KVLOAD1(vB, vbp, 5)
    VCONSUME1(vA, 4)
    VCONSUME1(vB, 5)

    // ---- stores last: attn (fp32) via static predication, then oh ----
    {
        int head = lane >> 4, lih = lane & 15;
        float* ab = attn + (((size_t)n * NHEADS + head) * K2) * HWp + yx;
#pragma unroll
        for (int kk = 0; kk < 25; ++kk)
            if ((kk & 15) == lih) ab[(size_t)kk * HWp] = l[kk];
    }

    *reinterpret_cast<uint32*>(qb) = pack2(acc0, acc1);   // oh, in-place
}

// ---------------------------------------------------------------------------
// Kernel 3: MFMA final projection. out[o][pix] = Wfc * oh[pix][c]^T.
// ---------------------------------------------------------------------------
__global__ __launch_bounds__(256) void fc_mfma(
    const ushort16* __restrict__ oh, const ushort16* __restrict__ wfcb,
    float* __restrict__ out)
{
    int blk = blockIdx.x;
    int gp0 = blk * 64;
    int n   = gp0 >> 12;
    int yx0 = gp0 & 4095;

    int lane = threadIdx.x & 63;
    int wid  = threadIdx.x >> 6;
    int wr = wid >> 1, wc = wid & 1;
    int p16 = lane & 15, kg = lane >> 4;

    const ushort16* ohb = oh + (size_t)gp0 * CC;

    f32x4 acc[4][2] = {};

#pragma unroll
    for (int k0 = 0; k0 < 128; k0 += 32) {
        bf16x8 A[4], B[2];
#pragma unroll
        for (int ai = 0; ai < 4; ++ai) {
            int o = wr * 64 + ai * 16 + p16;
            A[ai] = *reinterpret_cast<const bf16x8*>(&wfcb[o * 128 + k0 + kg * 8]);
        }
#pragma unroll
        for (int bj = 0; bj < 2; ++bj) {
            int px = wc * 32 + bj * 16 + p16;
            B[bj] = *reinterpret_cast<const bf16x8*>(&ohb[(size_t)px * CC + k0 + kg * 8]);
        }
#pragma unroll
        for (int ai = 0; ai < 4; ++ai)
#pragma unroll
            for (int bj = 0; bj < 2; ++bj)
                acc[ai][bj] = __builtin_amdgcn_mfma_f32_16x16x32_bf16(
                    A[ai], B[bj], acc[ai][bj], 0, 0, 0);
    }

    float* ob = out + (size_t)n * CC * HWp + yx0;
#pragma unroll
    for (int ai = 0; ai < 4; ++ai) {
        int o = wr * 64 + ai * 16 + kg * 4;
#pragma unroll
        for (int bj = 0; bj < 2; ++bj) {
            int px = wc * 32 + bj * 16 + p16;
#pragma unroll
            for (int r = 0; r < 4; ++r)
                ob[(size_t)(o + r) * HWp + px] = acc[ai][bj][r];
        }
    }
}

// ---------------------------------------------------------------------------
extern "C" void kernel_launch(void* const* d_in, const int* in_sizes, int n_in,
                              void* d_out, int out_size, void* d_ws, size_t ws_size,
                              hipStream_t stream)
{
    const float* q    = (const float*)d_in[0];
    const float* k    = (const float*)d_in[1];
    const float* v    = (const float*)d_in[2];
    const float* flow = (const float*)d_in[3];
    const float* Wq   = (const float*)d_in[4];
    const float* Wk   = (const float*)d_in[5];
    const float* Wv   = (const float*)d_in[6];
    const float* Wfc  = (const float*)d_in[7];

    float* out  = (float*)d_out;                          // [N][C][H][W]
    float* attn = out + (size_t)NB * CC * HWp;            // [N][NHEADS][K2][H][W]

    ushort16* ws = (ushort16*)d_ws;
    size_t slab = (size_t)NB * HWp * CC;
    ushort16* qp  = ws;                                   // q -> oh in-place
    ushort16* kp  = ws + slab;
    ushort16* vp  = ws + 2 * slab;
    ushort16* wbf = ws + 3 * slab;

    wconv_kernel<<<dim3(64), dim3(256), 0, stream>>>(Wq, Wk, Wv, Wfc, wbf);
    proj_mfma<<<dim3(768), dim3(256), 0, stream>>>(q, k, v, wbf, qp, kp, vp);
    attn_kernel<<<dim3(16384), dim3(64), 0, stream>>>(qp, kp, vp, flow, attn);
    fc_mfma<<<dim3(256), dim3(256), 0, stream>>>(qp, wbf + 3 * 16384, out);
}

// Round 10
// 58.996 us; speedup vs baseline: 1.3214x; 1.3214x over previous
//
#include <hip/hip_runtime.h>

constexpr int NB = 4;
constexpr int CC = 128;
constexpr int HH = 64;
constexpr int WW = 64;
constexpr int HWp = HH * WW;      // 4096
constexpr int NHEADS = 4;
constexpr int K2 = 25;

typedef unsigned int   uint32;
typedef unsigned short ushort16;
typedef __attribute__((ext_vector_type(8))) short bf16x8;
typedef __attribute__((ext_vector_type(4))) float f32x4;

__device__ __forceinline__ ushort16 f2bf(float x) {
    uint32 b = __float_as_uint(x);
    return (ushort16)((b + 0x7FFFu + ((b >> 16) & 1u)) >> 16);   // RNE
}
__device__ __forceinline__ uint32 pack2(float lo, float hi) {
    return ((uint32)f2bf(hi) << 16) | (uint32)f2bf(lo);
}
__device__ __forceinline__ float bf_lo(uint32 u) { return __uint_as_float(u << 16); }
__device__ __forceinline__ float bf_hi(uint32 u) { return __uint_as_float(u & 0xFFFF0000u); }

// ---------------------------------------------------------------------------
// Kernel 0: convert Wq/Wk/Wv/Wfc fp32 -> bf16 (row-major preserved).
// ---------------------------------------------------------------------------
__global__ __launch_bounds__(256) void wconv_kernel(
    const float* __restrict__ Wq, const float* __restrict__ Wk,
    const float* __restrict__ Wv, const float* __restrict__ Wfc,
    ushort16* __restrict__ wbf)
{
    int i = blockIdx.x * 256 + threadIdx.x;   // 0..16383
    int m = i >> 12;
    int j = i & 4095;
    const float* s = (m == 0) ? Wq : ((m == 1) ? Wk : ((m == 2) ? Wv : Wfc));
    float4 f = reinterpret_cast<const float4*>(s)[j];
    uint32 w0 = pack2(f.x, f.y);
    uint32 w1 = pack2(f.z, f.w);
    uint32* d = reinterpret_cast<uint32*>(wbf + (size_t)m * 16384);
    d[j * 2]     = w0;
    d[j * 2 + 1] = w1;
}

// ---------------------------------------------------------------------------
// Kernel 1: MFMA projections. C[out=128][pix] = W[128x128] * X[c=128][pix].
// grid = 3 * NB * 64 = 768 blocks, 256 threads (2x2 wave grid).
// ---------------------------------------------------------------------------
__global__ __launch_bounds__(256) void proj_mfma(
    const float* __restrict__ q, const float* __restrict__ k, const float* __restrict__ v,
    const ushort16* __restrict__ wbf,
    ushort16* __restrict__ qp, ushort16* __restrict__ kp, ushort16* __restrict__ vp)
{
    __shared__ __align__(16) ushort16 lx[64 * 132];

    int blk = blockIdx.x;
    int p   = blk >> 8;
    int rem = blk & 255;
    int n   = rem >> 6;
    int pt  = rem & 63;
    int pix0 = pt * 64;

    const float*    X  = (p == 0) ? q  : ((p == 1) ? k  : v);
    ushort16*       O  = (p == 0) ? qp : ((p == 1) ? kp : vp);
    const ushort16* Wb = wbf + (size_t)p * 16384;
    const float*    Xb = X + (size_t)n * CC * HWp + pix0;

    int lane = threadIdx.x & 63;
    int cg   = threadIdx.x >> 6;

#pragma unroll
    for (int i = 0; i < 16; ++i) {
        int c0 = i * 8 + cg * 2;
        float a = Xb[c0 * HWp + lane];
        float b = Xb[(c0 + 1) * HWp + lane];
        *reinterpret_cast<uint32*>(&lx[lane * 132 + c0]) = pack2(a, b);
    }
    __syncthreads();

    int wid = threadIdx.x >> 6;
    int wr  = wid >> 1, wc = wid & 1;
    int p16 = lane & 15, kg = lane >> 4;

    f32x4 acc[4][2] = {};

#pragma unroll
    for (int k0 = 0; k0 < 128; k0 += 32) {
        bf16x8 A[4], B[2];
#pragma unroll
        for (int ai = 0; ai < 4; ++ai) {
            int o = wr * 64 + ai * 16 + p16;
            A[ai] = *reinterpret_cast<const bf16x8*>(&Wb[o * 128 + k0 + kg * 8]);
        }
#pragma unroll
        for (int bj = 0; bj < 2; ++bj) {
            int px = wc * 32 + bj * 16 + p16;
            const ushort16* sp = &lx[px * 132 + k0 + kg * 8];
            struct { unsigned long long lo, hi; } t;
            t.lo = *reinterpret_cast<const unsigned long long*>(sp);
            t.hi = *reinterpret_cast<const unsigned long long*>(sp + 4);
            B[bj] = __builtin_bit_cast(bf16x8, t);
        }
#pragma unroll
        for (int ai = 0; ai < 4; ++ai)
#pragma unroll
            for (int bj = 0; bj < 2; ++bj)
                acc[ai][bj] = __builtin_amdgcn_mfma_f32_16x16x32_bf16(
                    A[ai], B[bj], acc[ai][bj], 0, 0, 0);
    }

    ushort16* Ob = O + (size_t)(n * HWp + pix0) * CC;
#pragma unroll
    for (int ai = 0; ai < 4; ++ai) {
        int ob = wr * 64 + ai * 16 + kg * 4;
#pragma unroll
        for (int bj = 0; bj < 2; ++bj) {
            int px = wc * 32 + bj * 16 + p16;
            uint32* dst = reinterpret_cast<uint32*>(&Ob[(size_t)px * CC + ob]);
            dst[0] = pack2(acc[ai][bj][0], acc[ai][bj][1]);
            dst[1] = pack2(acc[ai][bj][2], acc[ai][bj][3]);
        }
    }
}

// ---------------------------------------------------------------------------
// Kernel 2: fused flow sampling + multi-head attention with ASYNC LDS gather.
// 64-thread blocks (1 wave = 4 pixels, 16 lanes/pixel, 8 ch/lane).
// 4-slot LDS ring (24 KB), depth-3 counted vmcnt pipeline. Each slot rewrite
// is guarded by s_waitcnt lgkmcnt(0) AFTER the slot's ds_reads (prevents the
// ds_read vs DMA-write race). oh written IN-PLACE over qp.
// ---------------------------------------------------------------------------

#define WAITVM(N) { asm volatile("s_waitcnt vmcnt(" #N ")" ::: "memory"); \
                    __builtin_amdgcn_sched_barrier(0); }
#define LGKM0     { asm volatile("s_waitcnt lgkmcnt(0)" ::: "memory"); \
                    __builtin_amdgcn_sched_barrier(0); }

#define ISSUE(BASE, R, SLOT) { \
    const ushort16* rb_ = (BASE) + roff[R]; \
    _Pragma("unroll") \
    for (int rx = 0; rx < 6; ++rx) { \
        __builtin_amdgcn_global_load_lds( \
            (const __attribute__((address_space(1))) void*)(rb_ + coff[rx]), \
            (__attribute__((address_space(3))) void*)&lds[(SLOT) * 6144 + rx * 1024], \
            16, 0, 0); } }

#define DOT8(U) \
    fmaf(qv[7], bf_hi((U).w), fmaf(qv[6], bf_lo((U).w), \
    fmaf(qv[5], bf_hi((U).z), fmaf(qv[4], bf_lo((U).z), \
    fmaf(qv[3], bf_hi((U).y), fmaf(qv[2], bf_lo((U).y), \
    fmaf(qv[1], bf_hi((U).x), qv[0] * bf_lo((U).x))))))))

#define KC(SLOT, R) { \
    float pd_[6]; \
    _Pragma("unroll") \
    for (int rx = 0; rx < 6; ++rx) { \
        uint4 u_ = *reinterpret_cast<const uint4*>( \
            &lds[(SLOT) * 6144 + rx * 1024 + tid * 16]); \
        pd_[rx] = DOT8(u_); \
    } \
    float hbr_[5]; \
    _Pragma("unroll") \
    for (int kx = 0; kx < 5; ++kx) \
        hbr_[kx] = pd_[kx] * XA[kx] + pd_[kx + 1] * XB[kx + 1]; \
    if ((R) < 5) { \
        _Pragma("unroll") \
        for (int kx = 0; kx < 5; ++kx) l[(R) * 5 + kx] = hbr_[kx] * YT[R]; } \
    if ((R) >= 1) { \
        _Pragma("unroll") \
        for (int kx = 0; kx < 5; ++kx) \
            l[((R) - 1) * 5 + kx] = fmaf(hbr_[kx], YB[R], l[((R) - 1) * 5 + kx]); } }

#define VC(SLOT, R) { \
    float lhc_[6]; \
    if ((R) < 5) { \
        lhc_[0] = l[(R) * 5 + 0] * XA[0]; \
        _Pragma("unroll") \
        for (int rx = 1; rx < 5; ++rx) \
            lhc_[rx] = l[(R) * 5 + rx] * XA[rx] + l[(R) * 5 + rx - 1] * XB[rx]; \
        lhc_[5] = l[(R) * 5 + 4] * XB[5]; \
    } else { \
        _Pragma("unroll") \
        for (int rx = 0; rx < 6; ++rx) lhc_[rx] = 0.f; \
    } \
    _Pragma("unroll") \
    for (int rx = 0; rx < 6; ++rx) { \
        float w6_ = lhc_[rx] * YT[R] + lhp[rx] * YB[R]; \
        uint4 u_ = *reinterpret_cast<const uint4*>( \
            &lds[(SLOT) * 6144 + rx * 1024 + tid * 16]); \
        acc[0] = fmaf(bf_lo(u_.x), w6_, acc[0]); \
        acc[1] = fmaf(bf_hi(u_.x), w6_, acc[1]); \
        acc[2] = fmaf(bf_lo(u_.y), w6_, acc[2]); \
        acc[3] = fmaf(bf_hi(u_.y), w6_, acc[3]); \
        acc[4] = fmaf(bf_lo(u_.z), w6_, acc[4]); \
        acc[5] = fmaf(bf_hi(u_.z), w6_, acc[5]); \
        acc[6] = fmaf(bf_lo(u_.w), w6_, acc[6]); \
        acc[7] = fmaf(bf_hi(u_.w), w6_, acc[7]); \
    } \
    _Pragma("unroll") \
    for (int rx = 0; rx < 6; ++rx) lhp[rx] = lhc_[rx]; }

__global__ __launch_bounds__(64) void attn_kernel(
    ushort16* qoh,
    const ushort16* __restrict__ kp, const ushort16* __restrict__ vp,
    const float* __restrict__ flow,
    float* __restrict__ attn)
{
    __shared__ __align__(16) unsigned char lds[4 * 6144];   // 24 KB ring

    int blk = blockIdx.x;                        // 0..4095
    int swz = ((blk & 7) << 9) + (blk >> 3);     // XCD-contiguous bands
    int tid = threadIdx.x;                       // 0..63
    int pix = swz * 4 + (tid >> 4);              // global pixel 0..16383
    int lg  = tid & 15;
    int c0  = lg * 8;
    int n   = pix >> 12;
    int yx  = pix & 4095;
    int y   = yx >> 6, x = yx & 63;

    float fx = flow[((size_t)n * 2 + 0) * HWp + yx];
    float fy = flow[((size_t)n * 2 + 1) * HWp + yx];
    float pxf = (float)x + fx, pyf = (float)y + fy;
    float X0 = floorf(pxf), Y0 = floorf(pyf);
    float wx = pxf - X0,    wy = pyf - Y0;
    int ix0 = (int)X0 - 2,  iy0 = (int)Y0 - 2;

    int coff[6], roff[6];
    float XA[6], XB[6], YT[6], YB[6];
#pragma unroll
    for (int r = 0; r < 6; ++r) {
        int xi = ix0 + r;
        float mx = (xi >= 0 && xi < WW) ? 1.f : 0.f;
        int xc = xi < 0 ? 0 : (xi > WW - 1 ? WW - 1 : xi);
        coff[r] = xc * CC;
        XA[r] = (1.f - wx) * mx;
        XB[r] = wx * mx;
        int yi = iy0 + r;
        float my = (yi >= 0 && yi < HH) ? 1.f : 0.f;
        int yc = yi < 0 ? 0 : (yi > HH - 1 ? HH - 1 : yi);
        roff[r] = yc * (WW * CC);
        YT[r] = (1.f - wy) * my;
        YB[r] = wy * my;
    }

    const ushort16* kb  = kp + (size_t)n * HWp * CC + c0;
    const ushort16* vbp = vp + (size_t)n * HWp * CC + c0;
    ushort16* qb = qoh + (size_t)pix * CC + c0;

    uint4 qraw = *reinterpret_cast<const uint4*>(qb);
    float qv[8] = { bf_lo(qraw.x), bf_hi(qraw.x), bf_lo(qraw.y), bf_hi(qraw.y),
                    bf_lo(qraw.z), bf_hi(qraw.z), bf_lo(qraw.w), bf_hi(qraw.w) };

    // drain q/flow loads so vmcnt counts below are exact
    WAITVM(0);

    // prologue: 4 K rows in flight
    ISSUE(kb, 0, 0)
    ISSUE(kb, 1, 1)
    ISSUE(kb, 2, 2)
    ISSUE(kb, 3, 3)

    float l[25];
    WAITVM(18);  KC(0, 0)  LGKM0;  ISSUE(kb, 4, 0)
    WAITVM(18);  KC(1, 1)  LGKM0;  ISSUE(kb, 5, 1)
    WAITVM(18);  KC(2, 2)  LGKM0;  ISSUE(vbp, 0, 2)
    WAITVM(18);  KC(3, 3)  LGKM0;  ISSUE(vbp, 1, 3)
    WAITVM(18);  KC(0, 4)  LGKM0;  ISSUE(vbp, 2, 0)
    WAITVM(18);  KC(1, 5)  LGKM0;  ISSUE(vbp, 3, 1)

    // ---- reduce over 4 lanes (=32 ch) of this head; V DMAs in flight ----
#pragma unroll
    for (int kk = 0; kk < 25; ++kk) {
        float s = l[kk];
        s += __shfl_xor(s, 1);
        s += __shfl_xor(s, 2);
        l[kk] = s * 0.17677669529663687f;   // 1/sqrt(32)
    }

    // ---- softmax over 25 ----
    float m = l[0];
#pragma unroll
    for (int kk = 1; kk < 25; ++kk) m = fmaxf(m, l[kk]);
    float sum = 0.f;
#pragma unroll
    for (int kk = 0; kk < 25; ++kk) { l[kk] = __expf(l[kk] - m); sum += l[kk]; }
    float inv = 1.f / sum;
#pragma unroll
    for (int kk = 0; kk < 25; ++kk) l[kk] *= inv;

    // ---- V pass ----
    float acc[8] = {0.f, 0.f, 0.f, 0.f, 0.f, 0.f, 0.f, 0.f};
    float lhp[6] = {0.f, 0.f, 0.f, 0.f, 0.f, 0.f};
    WAITVM(18);  VC(2, 0)  LGKM0;  ISSUE(vbp, 4, 2)
    WAITVM(18);  VC(3, 1)  LGKM0;  ISSUE(vbp, 5, 3)
    WAITVM(12);  VC(0, 2)
    WAITVM(6);   VC(1, 3)
    WAITVM(0);   VC(2, 4)
                 VC(3, 5)

    // ---- stores last: attn (fp32, reference layout) then oh in-place ----
    {
        int head = lg >> 2, j = lg & 3;
        float* ab = attn + (((size_t)n * NHEADS + head) * K2) * HWp + yx;
#pragma unroll
        for (int kk = 0; kk < 25; ++kk)
            if ((kk & 3) == j) ab[(size_t)kk * HWp] = l[kk];
    }

    uint4 o;
    o.x = pack2(acc[0], acc[1]);
    o.y = pack2(acc[2], acc[3]);
    o.z = pack2(acc[4], acc[5]);
    o.w = pack2(acc[6], acc[7]);
    *reinterpret_cast<uint4*>(qb) = o;     // oh, in-place over qp
}

// ---------------------------------------------------------------------------
// Kernel 3: MFMA final projection. out[o][pix] = Wfc * oh[pix][c]^T.
// ---------------------------------------------------------------------------
__global__ __launch_bounds__(256) void fc_mfma(
    const ushort16* __restrict__ oh, const ushort16* __restrict__ wfcb,
    float* __restrict__ out)
{
    int blk = blockIdx.x;
    int gp0 = blk * 64;
    int n   = gp0 >> 12;
    int yx0 = gp0 & 4095;

    int lane = threadIdx.x & 63;
    int wid  = threadIdx.x >> 6;
    int wr = wid >> 1, wc = wid & 1;
    int p16 = lane & 15, kg = lane >> 4;

    const ushort16* ohb = oh + (size_t)gp0 * CC;

    f32x4 acc[4][2] = {};

#pragma unroll
    for (int k0 = 0; k0 < 128; k0 += 32) {
        bf16x8 A[4], B[2];
#pragma unroll
        for (int ai = 0; ai < 4; ++ai) {
            int o = wr * 64 + ai * 16 + p16;
            A[ai] = *reinterpret_cast<const bf16x8*>(&wfcb[o * 128 + k0 + kg * 8]);
        }
#pragma unroll
        for (int bj = 0; bj < 2; ++bj) {
            int px = wc * 32 + bj * 16 + p16;
            B[bj] = *reinterpret_cast<const bf16x8*>(&ohb[(size_t)px * CC + k0 + kg * 8]);
        }
#pragma unroll
        for (int ai = 0; ai < 4; ++ai)
#pragma unroll
            for (int bj = 0; bj < 2; ++bj)
                acc[ai][bj] = __builtin_amdgcn_mfma_f32_16x16x32_bf16(
                    A[ai], B[bj], acc[ai][bj], 0, 0, 0);
    }

    float* ob = out + (size_t)n * CC * HWp + yx0;
#pragma unroll
    for (int ai = 0; ai < 4; ++ai) {
        int o = wr * 64 + ai * 16 + kg * 4;
#pragma unroll
        for (int bj = 0; bj < 2; ++bj) {
            int px = wc * 32 + bj * 16 + p16;
#pragma unroll
            for (int r = 0; r < 4; ++r)
                ob[(size_t)(o + r) * HWp + px] = acc[ai][bj][r];
        }
    }
}

// ---------------------------------------------------------------------------
extern "C" void kernel_launch(void* const* d_in, const int* in_sizes, int n_in,
                              void* d_out, int out_size, void* d_ws, size_t ws_size,
                              hipStream_t stream)
{
    const float* q    = (const float*)d_in[0];
    const float* k    = (const float*)d_in[1];
    const float* v    = (const float*)d_in[2];
    const float* flow = (const float*)d_in[3];
    const float* Wq   = (const float*)d_in[4];
    const float* Wk   = (const float*)d_in[5];
    const float* Wv   = (const float*)d_in[6];
    const float* Wfc  = (const float*)d_in[7];

    float* out  = (float*)d_out;                          // [N][C][H][W]
    float* attn = out + (size_t)NB * CC * HWp;            // [N][NHEADS][K2][H][W]

    ushort16* ws = (ushort16*)d_ws;
    size_t slab = (size_t)NB * HWp * CC;
    ushort16* qp  = ws;                                   // q -> oh in-place
    ushort16* kp  = ws + slab;
    ushort16* vp  = ws + 2 * slab;
    ushort16* wbf = ws + 3 * slab;

    wconv_kernel<<<dim3(64), dim3(256), 0, stream>>>(Wq, Wk, Wv, Wfc, wbf);
    proj_mfma<<<dim3(768), dim3(256), 0, stream>>>(q, k, v, wbf, qp, kp, vp);
    attn_kernel<<<dim3(4096), dim3(64), 0, stream>>>(qp, kp, vp, flow, attn);
    fc_mfma<<<dim3(256), dim3(256), 0, stream>>>(qp, wbf + 3 * 16384, out);
}